// Round 4
// baseline (478.423 us; speedup 1.0000x reference)
//
#include <hip/hip_runtime.h>
#include <math.h>

#define B_ 16
#define W_ 512
#define H_ 512
#define S_ (W_*H_)
#define ALPHA_ 0.15f
#define MU_ 10.0f
#define TAU_ 0.125f
#define SIG_ 0.125f
#define EPS_ 1e-6f
#define INV1PT_ (1.0f/(1.0f+TAU_))
#define NBINS 4096
#define BINSCALE 2048.0f
#define BINW (1.0f/2048.0f)

// ---- K1: horizontal 31-tap max via log-tree sliding max ----
__global__ __launch_bounds__(256) void hmax_kernel(const float* __restrict__ Iy,
                                                   float* __restrict__ Rh,
                                                   float* __restrict__ GBh){
  __shared__ float bufA[2][544], bufB[2][544];
  int t = threadIdx.x;
  int b = blockIdx.x >> 9;
  int i = blockIdx.x & 511;
  const float* row = Iy + (size_t)b*3*S_ + (size_t)i*W_;
  for (int p = t; p < 544; p += 256){
    int idx = p - 16;
    bool v = (idx >= 0) && (idx < 512);
    bufA[0][p] = v ? row[idx] : -1e30f;
    bufA[1][p] = v ? fmaxf(row[S_+idx], row[2*S_+idx]) : -1e30f;
  }
  __syncthreads();
  float (*src)[544] = bufA; float (*dst)[544] = bufB;
  const int ds[5] = {1, 2, 4, 8, 15};
  #pragma unroll
  for (int sstep = 0; sstep < 5; ++sstep){
    int d = ds[sstep];
    for (int p = t; p < 544; p += 256){
      int q = min(p + d, 543);
      dst[0][p] = fmaxf(src[0][p], src[0][q]);
      dst[1][p] = fmaxf(src[1][p], src[1][q]);
    }
    __syncthreads();
    float (*tmp)[544] = src; src = dst; dst = tmp;
  }
  size_t o = (size_t)b*S_ + (size_t)i*W_;
  for (int p = t; p < 512; p += 256){
    Rh[o+p]  = src[0][p+1];
    GBh[o+p] = src[1][p+1];
  }
}

// ---- vertical van Herk forward scan (31-row aligned chunks) ----
__global__ __launch_bounds__(256) void vscan_fwd_kernel(const float* __restrict__ Rh,
                                                        const float* __restrict__ GBh,
                                                        float* __restrict__ Rf,
                                                        float* __restrict__ Gf){
  int gid = blockIdx.x*256 + threadIdx.x;     // 544 blocks = 8192 cols * 17 chunks
  int col = gid & 8191;
  int c   = gid >> 13;                        // 0..16
  int b = col >> 9, j = col & 511;
  int i0 = c*31, i1 = min(i0+31, H_);
  size_t base = (size_t)b*S_ + j;
  float rR = -1e30f, rG = -1e30f;
  for (int i = i0; i < i1; ++i){
    size_t o = base + (size_t)i*W_;
    rR = fmaxf(rR, Rh[o]); rG = fmaxf(rG, GBh[o]);
    Rf[o] = rR; Gf[o] = rG;
  }
}

// ---- vertical bwd scan; x = |Rmax - GBmax| + R ----
__global__ __launch_bounds__(256) void vscan_bwd_kernel(const float* __restrict__ Rh,
                                                        const float* __restrict__ GBh,
                                                        const float* __restrict__ Rf,
                                                        const float* __restrict__ Gf,
                                                        const float* __restrict__ Iy,
                                                        float* __restrict__ xo){
  int gid = blockIdx.x*256 + threadIdx.x;
  int col = gid & 8191;
  int c   = gid >> 13;
  int b = col >> 9, j = col & 511;
  int i0 = c*31, i1 = min(i0+31, H_);
  size_t base = (size_t)b*S_ + j;
  const float* IyR = Iy + (size_t)b*3*S_ + j;
  float lR = -1e30f, lG = -1e30f;
  for (int i = i1-1; i >= i0; --i){
    size_t o64 = base + (size_t)i*W_;
    lR = fmaxf(lR, Rh[o64]); lG = fmaxf(lG, GBh[o64]);
    int o = i + 15;
    if (o < H_){
      int bi = min(i + 30, H_-1);
      size_t ob = base + (size_t)bi*W_;
      float mR = fmaxf(lR, Rf[ob]);
      float mG = fmaxf(lG, Gf[ob]);
      xo[base + (size_t)o*W_] = fabsf(mR - mG) + IyR[(size_t)o*W_];
    }
  }
  if (c == 0){
    for (int o = 0; o < 15; ++o){
      size_t ob = base + (size_t)(o+15)*W_;
      float mR = Rf[ob], mG = Gf[ob];
      xo[base + (size_t)o*W_] = fabsf(mR - mG) + IyR[(size_t)o*W_];
    }
  }
}

// ---- per-block PARTIAL histograms of x ----
__global__ __launch_bounds__(256) void hist_build_kernel(const float* __restrict__ data,
                                                         unsigned int* __restrict__ hist){
  __shared__ unsigned int h[NBINS];
  int t = threadIdx.x;
  int b = blockIdx.x >> 4, sub = blockIdx.x & 15;
  for (int p = t; p < NBINS; p += 256) h[p] = 0u;
  __syncthreads();
  const float* p = data + (size_t)b*S_ + (size_t)sub*16384;
  for (int k = 0; k < 64; ++k){
    float x = p[k*256 + t];
    int bin = (int)(x*BINSCALE);
    bin = min(max(bin, 0), NBINS-1);
    atomicAdd(&h[bin], 1u);
  }
  __syncthreads();
  unsigned int* hb = hist + (size_t)(b*16 + sub)*NBINS;
  for (int q = t; q < NBINS; q += 256) hb[q] = h[q];
}

// ---- FUSED: N_hat store + grad-mag histogram in one pass over xb ----
// c values bitwise-identical to the old nhat_kernel; gm binning bitwise-identical
// to the old hist_gm_kernel (same float ops on the same values).
__global__ __launch_bounds__(256) void nhat_gmhist_kernel(const float* __restrict__ xb,
                                                          const float* __restrict__ vx2,
                                                          float* __restrict__ nh,
                                                          unsigned int* __restrict__ hist){
  __shared__ unsigned int h[NBINS];
  int t = threadIdx.x;
  int b = blockIdx.x >> 4, sub = blockIdx.x & 15;
  for (int p = t; p < NBINS; p += 256) h[p] = 0u;
  __syncthreads();
  float lo = vx2[2*b], hi = vx2[2*b+1];
  float inv = 1.0f/(hi - lo + EPS_);
  const float* base = xb + (size_t)b*S_;
  float* nhb = nh + (size_t)b*S_;
  int i0 = sub*16384;
  for (int k = 0; k < 64; ++k){
    int idx = i0 + k*256 + t;
    int row = idx >> 9, col = idx & 511;
    float c = fminf(fmaxf((base[idx] - lo)*inv, 0.f), 1.f);
    float dx = 0.f, dy = 0.f;
    if (col < W_-1) dx = fminf(fmaxf((base[idx+1]  - lo)*inv, 0.f), 1.f) - c;
    if (row < H_-1) dy = fminf(fmaxf((base[idx+W_] - lo)*inv, 0.f), 1.f) - c;
    nhb[idx] = c;
    float g = sqrtf(dx*dx + dy*dy + EPS_);
    int bin = (int)(g*BINSCALE);
    bin = min(max(bin, 0), NBINS-1);
    atomicAdd(&h[bin], 1u);
  }
  __syncthreads();
  unsigned int* hb = hist + (size_t)(b*16 + sub)*NBINS;
  for (int q = t; q < NBINS; q += 256) hb[q] = h[q];
}

// ---- pick order statistics ----
__global__ __launch_bounds__(256) void pick_hist_kernel(
    const unsigned int* __restrict__ hist, int r0, int r1, int r2, int r3,
    int nranks, float* __restrict__ outv, int which){
  __shared__ unsigned int part[256];
  __shared__ int s_own[4], s_rem[4];
  __shared__ float s_val[4];
  int t = threadIdx.x, b = blockIdx.x;
  const unsigned int* hb = hist + (size_t)b*16*NBINS;
  unsigned int binc[16];
  #pragma unroll
  for (int k = 0; k < 16; ++k) binc[k] = 0u;
  for (int sub = 0; sub < 16; ++sub){
    const unsigned int* hp = hb + (size_t)sub*NBINS + t*16;
    #pragma unroll
    for (int k = 0; k < 16; ++k) binc[k] += hp[k];
  }
  unsigned int sum = 0u;
  #pragma unroll
  for (int k = 0; k < 16; ++k) sum += binc[k];
  part[t] = sum;
  __syncthreads();
  if (t == 0){
    int rk[4] = {r0, r1, r2, r3};
    for (int ri = 0; ri < nranks; ++ri){
      int rem = rk[ri]; int own = 255;
      for (int q = 0; q < 256; ++q){
        if ((unsigned int)rem < part[q]){ own = q; break; }
        rem -= (int)part[q];
      }
      s_own[ri] = own; s_rem[ri] = rem;
    }
  }
  __syncthreads();
  for (int ri = 0; ri < nranks; ++ri){
    if (t == s_own[ri]){
      int rem = s_rem[ri]; int bin = t*16 + 15;
      #pragma unroll
      for (int q = 0; q < 16; ++q){
        if ((unsigned int)rem < binc[q]){ bin = t*16 + q; break; }
        rem -= (int)binc[q];
      }
      s_val[ri] = ((float)bin + 0.5f) * BINW;
    }
  }
  __syncthreads();
  if (t == 0){
    if (which == 0){
      outv[2*b+0] = s_val[0]*0.57f + s_val[1]*0.43f;   // lo (pos frac .43)
      outv[2*b+1] = s_val[2]*0.43f + s_val[3]*0.57f;   // hi (pos frac .57)
    } else {
      outv[b] = fmaxf(0.5f*(s_val[0] + s_val[1]), EPS_); // median -> sigma
    }
  }
}

// ---- fused primal-dual: TILE 64 / CORE 48 / 1024 thr / 1x4 px per thread ----
// __launch_bounds__ 2nd arg is (empirically, from VGPR counts across rounds)
// min WORKGROUPS per CU, CUDA-style: (1024,2) -> 2 WG x 16 waves = 32 waves/CU,
// VGPR cap 64. Round 3's (1024,8) forced a 32-VGPR budget -> scratch spills.
#define TILE 64
#define CORE 48
#define HALO 8
#define NB 11    // ceil(512/48)
#define PSTR 68  // padded LDS row stride; all hot accesses are row-aligned b128 (2-way, free)

#define AW_(d) (ALPHA_*(1.0f + MU_*__expf(-fabsf(d)*invs)))

__global__ __launch_bounds__(1024, 2) void pd_fused_kernel(
    const float* __restrict__ u_in,  const float* __restrict__ ub_in,
    const float* __restrict__ px_in, const float* __restrict__ py_in,
    float* __restrict__ u_out,  float* __restrict__ ub_out,
    float* __restrict__ px_out, float* __restrict__ py_out,
    const float* __restrict__ nh_g, const float* __restrict__ sig_arr,
    int T, int mode)   // mode 1 = init from nh; 2 = last launch (store clamped u)
{
  __shared__ float sA[TILE*PSTR], sB[TILE*PSTR];
  const int t = threadIdx.x;
  const int b = blockIdx.z;
  const int gi0 = blockIdx.y*CORE - HALO;
  const int gj0 = blockIdx.x*CORE - HALO;
  const float invs = 1.0f / sig_arr[b];
  const int pi = t >> 4, pj = t & 15;      // 64 rows x 16 col-groups
  const int c0 = 4*pj;                     // 1-tall x 4-wide pixels per thread
  const int lane = t & 63;
  const size_t bb = (size_t)b*S_;
  const int gi = gi0 + pi;

  // stage a full 64x64 tile (clamped-replicate halo), 4 scalar loads/thread
  #define STAGE(dst, srcP)                                         \
    _Pragma("unroll")                                              \
    for (int k = 0; k < 4; ++k){                                   \
      int p = t + k*1024; int li = p>>6, lj = p & 63;              \
      int sgi = gi0+li, sgj = gj0+lj;                              \
      int gic = min(max(sgi,0),H_-1), gjc = min(max(sgj,0),W_-1);  \
      dst[li*PSTR+lj] = srcP[bb + (size_t)gic*W_ + gjc]; }

  // nh tile -> sB (weights); ub init -> sA
  STAGE(sB, nh_g)
  if (mode == 1){ STAGE(sA, nh_g) }
  else          { STAGE(sA, ub_in) }
  __syncthreads();

  // loop-invariant LDS addresses (row-aligned b128 only in the hot loop)
  const int rU = max(pi-1,0), rD = min(pi+1,TILE-1);
  const int a_o  = pi*PSTR + c0;
  const int a_up = rU*PSTR + c0;
  const int a_dn = rD*PSTR + c0;

  // ---- prologue: weights from nh (in sB) ----
  float nh_r[4], ax[4], ay[4], ayU[4], axL;
  {
    const int cl = max(c0-1,0), cr = min(c0+4,TILE-1);
    float4 n0 = *(const float4*)&sB[a_o];
    float4 nU = *(const float4*)&sB[a_up];
    float4 nD = *(const float4*)&sB[a_dn];
    float nR = sB[pi*PSTR + cr], nL = sB[pi*PSTR + cl];
    float n0a[4] = {n0.x,n0.y,n0.z,n0.w};
    float nUa[4] = {nU.x,nU.y,nU.z,nU.w};
    float nDa[4] = {nD.x,nD.y,nD.z,nD.w};
    const int giU = gi - 1;
    #pragma unroll
    for (int c = 0; c < 4; ++c){
      nh_r[c] = n0a[c];
      int gj = gj0 + c0 + c;
      float nhR = (c<3) ? n0a[c+1] : nR;
      bool jb = (gj < 0) || (gj >= W_-1);
      ax[c]  = jb ? 0.f : AW_(nhR - n0a[c]);
      ay[c]  = (gi  < 0 || gi  >= H_-1) ? 0.f : AW_(nDa[c] - n0a[c]);
      ayU[c] = (giU < 0 || giU >= H_-1) ? 0.f : AW_(n0a[c] - nUa[c]);
    }
    int gjL = gj0 + c0 - 1;
    float nhRL = (c0 > 0) ? n0a[0] : n0a[1];
    bool lb = (gjL < 0) || (gjL >= W_-1);
    axL = lb ? 0.f : AW_(nhRL - nL);
  }

  // ---- state: u/px/py/pxL/pyU loaded DIRECTLY from global (no halo dependency;
  // out-of-range lanes are masked by ax/ay==0 so their values never propagate) ----
  float u_r[4], px_r[4], py_r[4], pyU[4], pxL, ub_r[4], ubw[4];
  if (mode == 1){
    #pragma unroll
    for (int c = 0; c < 4; ++c){
      u_r[c] = nh_r[c]; ub_r[c] = nh_r[c];
      px_r[c] = 0.f; py_r[c] = 0.f; pyU[c] = 0.f;
    }
    pxL = 0.f;
  } else {
    int gic  = min(max(gi,0),H_-1);
    int gicU = min(max(gi-1,0),H_-1);
    int gjc4 = min(max(gj0+c0,0), W_-4);           // stays multiple of 4
    size_t go  = bb + (size_t)gic *W_ + gjc4;
    size_t goU = bb + (size_t)gicU*W_ + gjc4;
    float4 uv  = *(const float4*)&u_in[go];
    float4 pxv = *(const float4*)&px_in[go];
    float4 pyv = *(const float4*)&py_in[go];
    float4 pyu = *(const float4*)&py_in[goU];
    u_r[0]=uv.x;  u_r[1]=uv.y;  u_r[2]=uv.z;  u_r[3]=uv.w;
    px_r[0]=pxv.x; px_r[1]=pxv.y; px_r[2]=pxv.z; px_r[3]=pxv.w;
    py_r[0]=pyv.x; py_r[1]=pyv.y; py_r[2]=pyv.z; py_r[3]=pyv.w;
    pyU[0]=pyu.x; pyU[1]=pyu.y; pyU[2]=pyu.z; pyU[3]=pyu.w;
    int gjLc = min(max(gj0+c0-1,0), W_-1);
    pxL = px_in[bb + (size_t)gic*W_ + gjLc];
    float4 ubv = *(const float4*)&sA[a_o];
    ub_r[0]=ubv.x; ub_r[1]=ubv.y; ub_r[2]=ubv.z; ub_r[3]=ubv.w;
  }
  __syncthreads();

  for (int s = 0; s < T; ++s){
    float* RB = (s & 1) ? sB : sA;
    float4 up = *(const float4*)&RB[a_up];
    float4 dn = *(const float4*)&RB[a_dn];
    // left/right neighbor ub via intra-wave shuffle of registers (same values as
    // the LDS reads they replace; tile-edge clamp reproduced exactly)
    float ubL = __shfl(ub_r[3], (lane-1)&63);
    float ubR = __shfl(ub_r[0], (lane+1)&63);
    if (pj == 0)  ubL = ub_r[0];
    if (pj == 15) ubR = ub_r[3];
    float upa[4] = {up.x,up.y,up.z,up.w};
    float dna[4] = {dn.x,dn.y,dn.z,dn.w};

    pxL = fminf(fmaxf(fmaf(SIG_, ub_r[0]-ubL, pxL), -axL), axL);
    #pragma unroll
    for (int c = 0; c < 4; ++c)
      pyU[c] = fminf(fmaxf(fmaf(SIG_, ub_r[c]-upa[c], pyU[c]), -ayU[c]), ayU[c]);
    #pragma unroll
    for (int c = 0; c < 4; ++c){
      float ubRn = (c<3) ? ub_r[c+1] : ubR;
      px_r[c] = fminf(fmaxf(fmaf(SIG_, ubRn-ub_r[c], px_r[c]), -ax[c]), ax[c]);
      py_r[c] = fminf(fmaxf(fmaf(SIG_, dna[c]-ub_r[c], py_r[c]), -ay[c]), ay[c]);
    }
    #pragma unroll
    for (int c = 0; c < 4; ++c){
      float pxl = (c>0) ? px_r[c-1] : pxL;
      float div = px_r[c] + py_r[c] - pxl - pyU[c];
      float un = fmaf(TAU_, div + nh_r[c], u_r[c]) * INV1PT_;
      ubw[c] = 2.f*un - u_r[c];
      u_r[c] = un;
    }
    ub_r[0]=ubw[0]; ub_r[1]=ubw[1]; ub_r[2]=ubw[2]; ub_r[3]=ubw[3];
    if (s < T-1){
      float* WB = (s & 1) ? sA : sB;
      *(float4*)&WB[a_o] = make_float4(ubw[0],ubw[1],ubw[2],ubw[3]);
      __syncthreads();
    }
  }

  // epilogue: core rows 8..55, core col-groups pj 2..13
  if (pi >= HALO && pi < HALO+CORE && pj >= 2 && pj <= 13 && gi < H_){
    int gj = gj0 + c0;
    if (gj < W_){
      size_t g = bb + (size_t)gi*W_ + gj;
      if (mode == 2){
        *(float4*)&u_out[g] = make_float4(
          fminf(fmaxf(u_r[0],0.f),1.f), fminf(fmaxf(u_r[1],0.f),1.f),
          fminf(fmaxf(u_r[2],0.f),1.f), fminf(fmaxf(u_r[3],0.f),1.f));
      } else {
        *(float4*)&u_out[g]  = make_float4(u_r[0], u_r[1], u_r[2], u_r[3]);
        *(float4*)&ub_out[g] = make_float4(ub_r[0],ub_r[1],ub_r[2],ub_r[3]);
        *(float4*)&px_out[g] = make_float4(px_r[0],px_r[1],px_r[2],px_r[3]);
        *(float4*)&py_out[g] = make_float4(py_r[0],py_r[1],py_r[2],py_r[3]);
      }
    }
  }
}

extern "C" void kernel_launch(void* const* d_in, const int* in_sizes, int n_in,
                              void* d_out, int out_size, void* d_ws, size_t ws_size,
                              hipStream_t stream){
  const float* Iy = (const float*)d_in[0];
  float* out = (float*)d_out;
  char* ws = (char*)d_ws;
  const size_t SLOT = (size_t)B_*S_*sizeof(float);
  float* slot[8];
  for (int q = 0; q < 8; ++q) slot[q] = (float*)(ws + (size_t)q*SLOT);
  float* vx2 = (float*)(ws + (size_t)8*SLOT);  // lo,hi per batch (32 floats)
  float* sig = vx2 + 32;                       // sigma per batch (16 floats)

  float* Rh  = slot[0];
  float* GBh = slot[1];
  float* Rf  = slot[5];
  float* Gf  = slot[6];
  float* xb  = slot[2];
  float* nh  = slot[3];
  unsigned int* hist_x  = (unsigned int*)(ws + (size_t)4*SLOT);   // 4 MiB
  unsigned int* hist_gm = hist_x + (size_t)256*NBINS;             // 4 MiB

  hmax_kernel<<<B_*H_, 256, 0, stream>>>(Iy, Rh, GBh);
  vscan_fwd_kernel<<<544, 256, 0, stream>>>(Rh, GBh, Rf, Gf);
  vscan_bwd_kernel<<<544, 256, 0, stream>>>(Rh, GBh, Rf, Gf, Iy, xb);
  hist_build_kernel<<<256, 256, 0, stream>>>(xb, hist_x);
  // ranks: floor/ceil of 0.01*(N-1)=2621.43 and 0.99*(N-1)=259521.57
  pick_hist_kernel<<<B_, 256, 0, stream>>>(hist_x, 2621, 2622, 259521, 259522, 4, vx2, 0);
  // fused N_hat store + grad-mag histogram (replaces nhat + hist_gm)
  nhat_gmhist_kernel<<<256, 256, 0, stream>>>(xb, vx2, nh, hist_gm);
  // median ranks 131071, 131072
  pick_hist_kernel<<<B_, 256, 0, stream>>>(hist_gm, 131071, 131072, 0, 0, 2, sig, 1);

  float *uA = slot[1], *ubA = slot[2], *pxA = slot[5], *pyA = slot[6];
  float *uB = slot[0], *ubB = slot[4], *pxB = slot[7], *pyB = out;

  dim3 pdg(NB, NB, B_);
  pd_fused_kernel<<<pdg, 1024, 0, stream>>>(nh, nh, nh, nh,
                                            uA, ubA, pxA, pyA, nh, sig, 8, 1);
  pd_fused_kernel<<<pdg, 1024, 0, stream>>>(uA, ubA, pxA, pyA,
                                            uB, ubB, pxB, pyB, nh, sig, 8, 0);
  pd_fused_kernel<<<pdg, 1024, 0, stream>>>(uB, ubB, pxB, pyB,
                                            uA, ubA, pxA, pyA, nh, sig, 8, 0);
  // last launch: clamp u straight into out (out not read in this launch)
  pd_fused_kernel<<<pdg, 1024, 0, stream>>>(uA, ubA, pxA, pyA,
                                            out, slot[7], slot[7], slot[7], nh, sig, 6, 2);
}

// Round 5
// 400.275 us; speedup vs baseline: 1.1952x; 1.1952x over previous
//
#include <hip/hip_runtime.h>
#include <math.h>

#define B_ 16
#define W_ 512
#define H_ 512
#define S_ (W_*H_)
#define ALPHA_ 0.15f
#define MU_ 10.0f
#define TAU_ 0.125f
#define SIG_ 0.125f
#define EPS_ 1e-6f
#define INV1PT_ (1.0f/(1.0f+TAU_))
#define NBINS 4096
#define BINSCALE 2048.0f
#define BINW (1.0f/2048.0f)

// ---- K1: horizontal 31-tap max via log-tree sliding max ----
__global__ __launch_bounds__(256) void hmax_kernel(const float* __restrict__ Iy,
                                                   float* __restrict__ Rh,
                                                   float* __restrict__ GBh){
  __shared__ float bufA[2][544], bufB[2][544];
  int t = threadIdx.x;
  int b = blockIdx.x >> 9;
  int i = blockIdx.x & 511;
  const float* row = Iy + (size_t)b*3*S_ + (size_t)i*W_;
  for (int p = t; p < 544; p += 256){
    int idx = p - 16;
    bool v = (idx >= 0) && (idx < 512);
    bufA[0][p] = v ? row[idx] : -1e30f;
    bufA[1][p] = v ? fmaxf(row[S_+idx], row[2*S_+idx]) : -1e30f;
  }
  __syncthreads();
  float (*src)[544] = bufA; float (*dst)[544] = bufB;
  const int ds[5] = {1, 2, 4, 8, 15};
  #pragma unroll
  for (int sstep = 0; sstep < 5; ++sstep){
    int d = ds[sstep];
    for (int p = t; p < 544; p += 256){
      int q = min(p + d, 543);
      dst[0][p] = fmaxf(src[0][p], src[0][q]);
      dst[1][p] = fmaxf(src[1][p], src[1][q]);
    }
    __syncthreads();
    float (*tmp)[544] = src; src = dst; dst = tmp;
  }
  size_t o = (size_t)b*S_ + (size_t)i*W_;
  for (int p = t; p < 512; p += 256){
    Rh[o+p]  = src[0][p+1];
    GBh[o+p] = src[1][p+1];
  }
}

// ---- vertical van Herk forward scan (31-row aligned chunks) ----
__global__ __launch_bounds__(256) void vscan_fwd_kernel(const float* __restrict__ Rh,
                                                        const float* __restrict__ GBh,
                                                        float* __restrict__ Rf,
                                                        float* __restrict__ Gf){
  int gid = blockIdx.x*256 + threadIdx.x;     // 544 blocks = 8192 cols * 17 chunks
  int col = gid & 8191;
  int c   = gid >> 13;                        // 0..16
  int b = col >> 9, j = col & 511;
  int i0 = c*31, i1 = min(i0+31, H_);
  size_t base = (size_t)b*S_ + j;
  float rR = -1e30f, rG = -1e30f;
  for (int i = i0; i < i1; ++i){
    size_t o = base + (size_t)i*W_;
    rR = fmaxf(rR, Rh[o]); rG = fmaxf(rG, GBh[o]);
    Rf[o] = rR; Gf[o] = rG;
  }
}

// ---- vertical bwd scan; x = |Rmax - GBmax| + R ----
__global__ __launch_bounds__(256) void vscan_bwd_kernel(const float* __restrict__ Rh,
                                                        const float* __restrict__ GBh,
                                                        const float* __restrict__ Rf,
                                                        const float* __restrict__ Gf,
                                                        const float* __restrict__ Iy,
                                                        float* __restrict__ xo){
  int gid = blockIdx.x*256 + threadIdx.x;
  int col = gid & 8191;
  int c   = gid >> 13;
  int b = col >> 9, j = col & 511;
  int i0 = c*31, i1 = min(i0+31, H_);
  size_t base = (size_t)b*S_ + j;
  const float* IyR = Iy + (size_t)b*3*S_ + j;
  float lR = -1e30f, lG = -1e30f;
  for (int i = i1-1; i >= i0; --i){
    size_t o64 = base + (size_t)i*W_;
    lR = fmaxf(lR, Rh[o64]); lG = fmaxf(lG, GBh[o64]);
    int o = i + 15;
    if (o < H_){
      int bi = min(i + 30, H_-1);
      size_t ob = base + (size_t)bi*W_;
      float mR = fmaxf(lR, Rf[ob]);
      float mG = fmaxf(lG, Gf[ob]);
      xo[base + (size_t)o*W_] = fabsf(mR - mG) + IyR[(size_t)o*W_];
    }
  }
  if (c == 0){
    for (int o = 0; o < 15; ++o){
      size_t ob = base + (size_t)(o+15)*W_;
      float mR = Rf[ob], mG = Gf[ob];
      xo[base + (size_t)o*W_] = fabsf(mR - mG) + IyR[(size_t)o*W_];
    }
  }
}

// ---- per-block PARTIAL histograms of x ----
__global__ __launch_bounds__(256) void hist_build_kernel(const float* __restrict__ data,
                                                         unsigned int* __restrict__ hist){
  __shared__ unsigned int h[NBINS];
  int t = threadIdx.x;
  int b = blockIdx.x >> 4, sub = blockIdx.x & 15;
  for (int p = t; p < NBINS; p += 256) h[p] = 0u;
  __syncthreads();
  const float* p = data + (size_t)b*S_ + (size_t)sub*16384;
  for (int k = 0; k < 64; ++k){
    float x = p[k*256 + t];
    int bin = (int)(x*BINSCALE);
    bin = min(max(bin, 0), NBINS-1);
    atomicAdd(&h[bin], 1u);
  }
  __syncthreads();
  unsigned int* hb = hist + (size_t)(b*16 + sub)*NBINS;
  for (int q = t; q < NBINS; q += 256) hb[q] = h[q];
}

// ---- FUSED: N_hat store + grad-mag histogram in one pass over xb ----
__global__ __launch_bounds__(256) void nhat_gmhist_kernel(const float* __restrict__ xb,
                                                          const float* __restrict__ vx2,
                                                          float* __restrict__ nh,
                                                          unsigned int* __restrict__ hist){
  __shared__ unsigned int h[NBINS];
  int t = threadIdx.x;
  int b = blockIdx.x >> 4, sub = blockIdx.x & 15;
  for (int p = t; p < NBINS; p += 256) h[p] = 0u;
  __syncthreads();
  float lo = vx2[2*b], hi = vx2[2*b+1];
  float inv = 1.0f/(hi - lo + EPS_);
  const float* base = xb + (size_t)b*S_;
  float* nhb = nh + (size_t)b*S_;
  int i0 = sub*16384;
  for (int k = 0; k < 64; ++k){
    int idx = i0 + k*256 + t;
    int row = idx >> 9, col = idx & 511;
    float c = fminf(fmaxf((base[idx] - lo)*inv, 0.f), 1.f);
    float dx = 0.f, dy = 0.f;
    if (col < W_-1) dx = fminf(fmaxf((base[idx+1]  - lo)*inv, 0.f), 1.f) - c;
    if (row < H_-1) dy = fminf(fmaxf((base[idx+W_] - lo)*inv, 0.f), 1.f) - c;
    nhb[idx] = c;
    float g = sqrtf(dx*dx + dy*dy + EPS_);
    int bin = (int)(g*BINSCALE);
    bin = min(max(bin, 0), NBINS-1);
    atomicAdd(&h[bin], 1u);
  }
  __syncthreads();
  unsigned int* hb = hist + (size_t)(b*16 + sub)*NBINS;
  for (int q = t; q < NBINS; q += 256) hb[q] = h[q];
}

// ---- pick order statistics ----
__global__ __launch_bounds__(256) void pick_hist_kernel(
    const unsigned int* __restrict__ hist, int r0, int r1, int r2, int r3,
    int nranks, float* __restrict__ outv, int which){
  __shared__ unsigned int part[256];
  __shared__ int s_own[4], s_rem[4];
  __shared__ float s_val[4];
  int t = threadIdx.x, b = blockIdx.x;
  const unsigned int* hb = hist + (size_t)b*16*NBINS;
  unsigned int binc[16];
  #pragma unroll
  for (int k = 0; k < 16; ++k) binc[k] = 0u;
  for (int sub = 0; sub < 16; ++sub){
    const unsigned int* hp = hb + (size_t)sub*NBINS + t*16;
    #pragma unroll
    for (int k = 0; k < 16; ++k) binc[k] += hp[k];
  }
  unsigned int sum = 0u;
  #pragma unroll
  for (int k = 0; k < 16; ++k) sum += binc[k];
  part[t] = sum;
  __syncthreads();
  if (t == 0){
    int rk[4] = {r0, r1, r2, r3};
    for (int ri = 0; ri < nranks; ++ri){
      int rem = rk[ri]; int own = 255;
      for (int q = 0; q < 256; ++q){
        if ((unsigned int)rem < part[q]){ own = q; break; }
        rem -= (int)part[q];
      }
      s_own[ri] = own; s_rem[ri] = rem;
    }
  }
  __syncthreads();
  for (int ri = 0; ri < nranks; ++ri){
    if (t == s_own[ri]){
      int rem = s_rem[ri]; int bin = t*16 + 15;
      #pragma unroll
      for (int q = 0; q < 16; ++q){
        if ((unsigned int)rem < binc[q]){ bin = t*16 + q; break; }
        rem -= (int)binc[q];
      }
      s_val[ri] = ((float)bin + 0.5f) * BINW;
    }
  }
  __syncthreads();
  if (t == 0){
    if (which == 0){
      outv[2*b+0] = s_val[0]*0.57f + s_val[1]*0.43f;   // lo (pos frac .43)
      outv[2*b+1] = s_val[2]*0.43f + s_val[3]*0.57f;   // hi (pos frac .57)
    } else {
      outv[b] = fmaxf(0.5f*(s_val[0] + s_val[1]), EPS_); // median -> sigma
    }
  }
}

// ---- fused primal-dual: TILE 64 / CORE 48 / 1024 thr / 1x4 px per thread ----
// State cut: pyU == up-neighbor's py (same update+clamp), pxL == left-neighbor's
// px[3]. Dual-state (pyU/ayU/pxL/axL, 10 regs) replaced by LDS publish of py
// (+1 barrier/iter) and an intra-wave shuffle. nh weights direct-loaded from
// global (L3-resident) instead of LDS staging. All value differences vs the
// old scheme sit >= 8 px from the core with T <= 8 -> core bit-identical.
#define TILE 64
#define CORE 48
#define HALO 8
#define NB 11    // ceil(512/48)
#define PSTR 68  // padded LDS row stride (float4-aligned)

#define AW_(d) (ALPHA_*(1.0f + MU_*__expf(-fabsf(d)*invs)))

__global__ __launch_bounds__(1024, 2) void pd_fused_kernel(
    const float* __restrict__ u_in,  const float* __restrict__ ub_in,
    const float* __restrict__ px_in, const float* __restrict__ py_in,
    float* __restrict__ u_out,  float* __restrict__ ub_out,
    float* __restrict__ px_out, float* __restrict__ py_out,
    const float* __restrict__ nh_g, const float* __restrict__ sig_arr,
    int T, int mode)   // mode 1 = init from nh; 2 = last launch (store clamped u)
{
  __shared__ float sA[TILE*PSTR], sB[TILE*PSTR], sP[TILE*PSTR];
  const int t = threadIdx.x;
  const int b = blockIdx.z;
  const int gi0 = blockIdx.y*CORE - HALO;
  const int gj0 = blockIdx.x*CORE - HALO;
  const float invs = 1.0f / sig_arr[b];
  const int pi = t >> 4, pj = t & 15;      // 64 rows x 16 col-groups
  const int c0 = 4*pj;                     // 1x4 px per thread
  const int lane = t & 63;
  const size_t bb = (size_t)b*S_;
  const int gi = gi0 + pi;

  // stage a full 64x64 tile (clamped-replicate halo), 4 scalar loads/thread
  #define STAGE(dst, srcP)                                         \
    _Pragma("unroll")                                              \
    for (int k = 0; k < 4; ++k){                                   \
      int p = t + k*1024; int li = p>>6, lj = p & 63;              \
      int sgi = gi0+li, sgj = gj0+lj;                              \
      int gic_ = min(max(sgi,0),H_-1), gjc_ = min(max(sgj,0),W_-1);\
      dst[li*PSTR+lj] = srcP[bb + (size_t)gic_*W_ + gjc_]; }

  // ub (or nh-as-ub) tile -> sA; sB/sP start dead
  if (mode == 1){ STAGE(sA, nh_g) }
  else          { STAGE(sA, ub_in) }

  // loop-invariant LDS addresses (row-aligned b128 in the hot loop)
  const int rD = min(pi+1,TILE-1);
  const int a_o  = pi*PSTR + c0;
  const int a_up = max(pi-1,0)*PSTR + c0;
  const int a_dn = rD*PSTR + c0;

  // ---- prologue: weights from nh, direct global loads (tile-clamp then
  // image-clamp reproduces old staged semantics at every core-feeding site) ----
  int gic  = min(max(gi,0),H_-1);
  int gjc4 = min(max(gj0+c0,0), W_-4);            // aligned float4 col
  size_t go = bb + (size_t)gic*W_ + gjc4;
  float nh_r[4], ax[4], ay[4];
  {
    int giD = min(max(min(gi+1, gi0+TILE-1),0),H_-1);
    int gjR = min(max(min(gj0+c0+4, gj0+TILE-1),0),W_-1);
    float4 n0 = *(const float4*)&nh_g[go];
    float4 nD = *(const float4*)&nh_g[bb + (size_t)giD*W_ + gjc4];
    float nR = nh_g[bb + (size_t)gic*W_ + gjR];
    float n0a[4] = {n0.x,n0.y,n0.z,n0.w};
    float nDa[4] = {nD.x,nD.y,nD.z,nD.w};
    #pragma unroll
    for (int c = 0; c < 4; ++c){
      nh_r[c] = n0a[c];
      int gj = gj0 + c0 + c;
      float nhR = (c<3) ? n0a[c+1] : nR;
      bool jb = (gj < 0) || (gj >= W_-1);
      ax[c] = jb ? 0.f : AW_(nhR - n0a[c]);
      ay[c] = (gi < 0 || gi >= H_-1) ? 0.f : AW_(nDa[c] - n0a[c]);
    }
  }

  // ---- state ----
  float u_r[4], px_r[4], py_r[4], ub_r[4];
  if (mode == 1){
    #pragma unroll
    for (int c = 0; c < 4; ++c){
      u_r[c] = nh_r[c]; ub_r[c] = nh_r[c];
      px_r[c] = 0.f; py_r[c] = 0.f;
    }
  } else {
    float4 uv  = *(const float4*)&u_in[go];
    float4 pxv = *(const float4*)&px_in[go];
    float4 pyv = *(const float4*)&py_in[go];
    u_r[0]=uv.x;  u_r[1]=uv.y;  u_r[2]=uv.z;  u_r[3]=uv.w;
    px_r[0]=pxv.x; px_r[1]=pxv.y; px_r[2]=pxv.z; px_r[3]=pxv.w;
    py_r[0]=pyv.x; py_r[1]=pyv.y; py_r[2]=pyv.z; py_r[3]=pyv.w;
  }
  __syncthreads();           // sA staged
  if (mode != 1){
    float4 ubv = *(const float4*)&sA[a_o];
    ub_r[0]=ubv.x; ub_r[1]=ubv.y; ub_r[2]=ubv.z; ub_r[3]=ubv.w;
  }

  for (int s = 0; s < T; ++s){
    float* RB = (s & 1) ? sB : sA;
    float* WB = (s & 1) ? sA : sB;
    float4 dn = *(const float4*)&RB[a_dn];
    float ubL = __shfl(ub_r[3], (lane-1)&63);
    float ubR = __shfl(ub_r[0], (lane+1)&63);
    if (pj == 0)  ubL = ub_r[0];
    if (pj == 15) ubR = ub_r[3];
    (void)ubL;
    float dna[4] = {dn.x,dn.y,dn.z,dn.w};
    #pragma unroll
    for (int c = 0; c < 4; ++c){
      float ubRn = (c<3) ? ub_r[c+1] : ubR;
      px_r[c] = fminf(fmaxf(fmaf(SIG_, ubRn-ub_r[c], px_r[c]), -ax[c]), ax[c]);
      py_r[c] = fminf(fmaxf(fmaf(SIG_, dna[c]-ub_r[c], py_r[c]), -ay[c]), ay[c]);
    }
    *(float4*)&sP[a_o] = make_float4(py_r[0],py_r[1],py_r[2],py_r[3]);
    float pxl3 = __shfl(px_r[3], (lane-1)&63);
    __syncthreads();                               // publish py
    float4 pu = *(const float4*)&sP[a_up];
    float pyu[4] = {pu.x,pu.y,pu.z,pu.w};
    #pragma unroll
    for (int c = 0; c < 4; ++c){
      float pxl = (c>0) ? px_r[c-1] : pxl3;
      float div = px_r[c] + py_r[c] - pxl - pyu[c];
      float un = fmaf(TAU_, div + nh_r[c], u_r[c]) * INV1PT_;
      ub_r[c] = 2.f*un - u_r[c];
      u_r[c] = un;
    }
    if (s < T-1){
      *(float4*)&WB[a_o] = make_float4(ub_r[0],ub_r[1],ub_r[2],ub_r[3]);
      __syncthreads();                             // publish ub
    }
  }

  // epilogue: core rows 8..55, core col-groups pj 2..13
  if (pi >= HALO && pi < HALO+CORE && pj >= 2 && pj <= 13 && gi < H_){
    int gj = gj0 + c0;
    if (gj < W_){
      size_t g = bb + (size_t)gi*W_ + gj;
      if (mode == 2){
        *(float4*)&u_out[g] = make_float4(
          fminf(fmaxf(u_r[0],0.f),1.f), fminf(fmaxf(u_r[1],0.f),1.f),
          fminf(fmaxf(u_r[2],0.f),1.f), fminf(fmaxf(u_r[3],0.f),1.f));
      } else {
        *(float4*)&u_out[g]  = make_float4(u_r[0], u_r[1], u_r[2], u_r[3]);
        *(float4*)&ub_out[g] = make_float4(ub_r[0],ub_r[1],ub_r[2],ub_r[3]);
        *(float4*)&px_out[g] = make_float4(px_r[0],px_r[1],px_r[2],px_r[3]);
        *(float4*)&py_out[g] = make_float4(py_r[0],py_r[1],py_r[2],py_r[3]);
      }
    }
  }
}

extern "C" void kernel_launch(void* const* d_in, const int* in_sizes, int n_in,
                              void* d_out, int out_size, void* d_ws, size_t ws_size,
                              hipStream_t stream){
  const float* Iy = (const float*)d_in[0];
  float* out = (float*)d_out;
  char* ws = (char*)d_ws;
  const size_t SLOT = (size_t)B_*S_*sizeof(float);
  float* slot[8];
  for (int q = 0; q < 8; ++q) slot[q] = (float*)(ws + (size_t)q*SLOT);
  float* vx2 = (float*)(ws + (size_t)8*SLOT);  // lo,hi per batch (32 floats)
  float* sig = vx2 + 32;                       // sigma per batch (16 floats)

  float* Rh  = slot[0];
  float* GBh = slot[1];
  float* Rf  = slot[5];
  float* Gf  = slot[6];
  float* xb  = slot[2];
  float* nh  = slot[3];
  unsigned int* hist_x  = (unsigned int*)(ws + (size_t)4*SLOT);   // 4 MiB
  unsigned int* hist_gm = hist_x + (size_t)256*NBINS;             // 4 MiB

  hmax_kernel<<<B_*H_, 256, 0, stream>>>(Iy, Rh, GBh);
  vscan_fwd_kernel<<<544, 256, 0, stream>>>(Rh, GBh, Rf, Gf);
  vscan_bwd_kernel<<<544, 256, 0, stream>>>(Rh, GBh, Rf, Gf, Iy, xb);
  hist_build_kernel<<<256, 256, 0, stream>>>(xb, hist_x);
  // ranks: floor/ceil of 0.01*(N-1)=2621.43 and 0.99*(N-1)=259521.57
  pick_hist_kernel<<<B_, 256, 0, stream>>>(hist_x, 2621, 2622, 259521, 259522, 4, vx2, 0);
  // fused N_hat store + grad-mag histogram
  nhat_gmhist_kernel<<<256, 256, 0, stream>>>(xb, vx2, nh, hist_gm);
  // median ranks 131071, 131072
  pick_hist_kernel<<<B_, 256, 0, stream>>>(hist_gm, 131071, 131072, 0, 0, 2, sig, 1);

  float *uA = slot[1], *ubA = slot[2], *pxA = slot[5], *pyA = slot[6];
  float *uB = slot[0], *ubB = slot[4], *pxB = slot[7], *pyB = out;

  dim3 pdg(NB, NB, B_);
  pd_fused_kernel<<<pdg, 1024, 0, stream>>>(nh, nh, nh, nh,
                                            uA, ubA, pxA, pyA, nh, sig, 8, 1);
  pd_fused_kernel<<<pdg, 1024, 0, stream>>>(uA, ubA, pxA, pyA,
                                            uB, ubB, pxB, pyB, nh, sig, 8, 0);
  pd_fused_kernel<<<pdg, 1024, 0, stream>>>(uB, ubB, pxB, pyB,
                                            uA, ubA, pxA, pyA, nh, sig, 8, 0);
  // last launch: clamp u straight into out (out not read in this launch)
  pd_fused_kernel<<<pdg, 1024, 0, stream>>>(uA, ubA, pxA, pyA,
                                            out, slot[7], slot[7], slot[7], nh, sig, 6, 2);
}